// Round 9
// baseline (543.212 us; speedup 1.0000x reference)
//
#include <hip/hip_runtime.h>

// Input (16,32,382,255) f32 ; output tensor (16,32,765,765) f32
// + u_min/u_max/v_min/v_max (16 each) written as floats after the tensor.
//
// Gather inversion: out[b,c,u,v] = in[b,c,u-ulo,v-vlo] when (u-ulo) in [0,382)
// and (v-vlo) in [0,255) else 0;  ulo = 255 - (q - r/2), vlo = 382 - r.
//
// Persistent-loop structure (mimics the 6.5 TB/s fill kernel): each block
// loads offsets once, then loops ~96 rows issuing back-to-back aligned
// float4 stores; waves stay resident -> store pipeline stays full.
namespace {
constexpr int kC = 32;
constexpr int kH = 382;              // input rows
constexpr int kW = 255;              // input cols
constexpr int kS = 765;              // output edge
constexpr int kPlaneIn  = kH * kW;   // 97410
constexpr int kPlaneOut = kS * kS;   // 585225  (== 1 mod 4)
constexpr int kNPlanes  = 16 * kC;   // 512
constexpr int kBlocksPerPlane = 8;
constexpr int kRowsPerBlock   = 96;  // 8*96 = 768 >= 765
constexpr int kThreads = 192;        // 3 waves; 191 f4 slots + double-duty extras
constexpr unsigned long long kOutElems =
    (unsigned long long)kNPlanes * (unsigned long long)kPlaneOut;
}

__global__ __launch_bounds__(kThreads) void axial_persist_kernel(
    const float* __restrict__ in, const int* __restrict__ off,
    float* __restrict__ out)
{
    const unsigned bid   = blockIdx.x;
    const unsigned plane = bid >> 3;          // 0..511 (b*32 + c)
    const unsigned k     = bid & 7u;          // row-chunk within plane
    const unsigned b     = plane >> 5;

    // Loaded ONCE per block, amortized over the row loop.
    const int q   = off[2u * b];
    const int r   = off[2u * b + 1u];
    const int ulo = 255 - (q - (r >> 1));     // first copy row, in [1,382]
    const int vlo = 382 - r;                  // first valid col

    const int t  = (int)threadIdx.x;
    const int t4 = t << 2;

    const int j0 = (int)k * kRowsPerBlock;
    const int j1 = (j0 + kRowsPerBlock < kS) ? j0 + kRowsPerBlock : kS;

    const float* __restrict__ inplane  = in  + (size_t)plane * (size_t)kPlaneIn;
    float* __restrict__       outplane = out + (size_t)plane * (size_t)kPlaneOut;

    const float4 zero4 = {0.f, 0.f, 0.f, 0.f};

#pragma unroll 2
    for (int j = j0; j < j1; ++j) {
        // j < 383: zero rows (u < ulo or u >= ulo+382); j >= 383: copy rows.
        const bool crow = (j >= 383);
        const int  h    = j - 383;                       // input row (copy rows)
        const int  u    = crow ? (ulo + h) : ((j < ulo) ? j : j + 382);

        float* __restrict__ orow = outplane + (size_t)u * (size_t)kS;
        // global dword index of row start mod 4 == (plane + u) & 3
        const int pad    = (-(int)(plane + (unsigned)u)) & 3;
        const int nvec   = (kS - pad) >> 2;              // 190 or 191
        const int nextra = kS - 4 * nvec;                // 1 or 5

        if (!crow) {
            if (t < nvec)
                *reinterpret_cast<float4*>(orow + pad + t4) = zero4;
            if (t < nextra) {
                const int d = (t < pad) ? t : 4 * nvec + t;
                orow[d] = 0.f;
            }
        } else {
            const float* __restrict__ inrow = inplane + (size_t)h * (size_t)kW;
            if (t < nvec) {
                const int d0   = pad + t4;
                const int rel0 = d0 - vlo;               // input col of comp 0
                float v0 = 0.f, v1 = 0.f, v2 = 0.f, v3 = 0.f;
                if (rel0 >= 0 && rel0 + 3 < kW) {        // interior of copy span
                    v0 = inrow[rel0];
                    v1 = inrow[rel0 + 1];
                    v2 = inrow[rel0 + 2];
                    v3 = inrow[rel0 + 3];
                } else if (rel0 + 3 >= 0 && rel0 < kW) { // straddles an edge
                    if ((unsigned)(rel0    ) < (unsigned)kW) v0 = inrow[rel0];
                    if ((unsigned)(rel0 + 1) < (unsigned)kW) v1 = inrow[rel0 + 1];
                    if ((unsigned)(rel0 + 2) < (unsigned)kW) v2 = inrow[rel0 + 2];
                    if ((unsigned)(rel0 + 3) < (unsigned)kW) v3 = inrow[rel0 + 3];
                }
                float4 val = {v0, v1, v2, v3};
                *reinterpret_cast<float4*>(orow + d0) = val;
            }
            if (t < nextra) {
                const int d   = (t < pad) ? t : 4 * nvec + t;
                const int rel = d - vlo;
                float sv = 0.f;
                if ((unsigned)rel < (unsigned)kW) sv = inrow[rel];
                orow[d] = sv;
            }
        }
    }
}

// u_min = 255 - uoff ; u_max = u_min + 382 ; v_min = 382 - r ; v_max = v_min + 255
__global__ void axial_extras_kernel(const int* __restrict__ off,
                                    float* __restrict__ out_tail)
{
    int i = threadIdx.x;          // 0..63
    if (i >= 64) return;
    int b = i & 15;
    int which = i >> 4;           // 0:u_min 1:u_max 2:v_min 3:v_max
    int q = off[2 * b];
    int r = off[2 * b + 1];
    int uoff = q - (r >> 1);
    int u_min = 255 - uoff;
    int v_min = 382 - r;
    int val = (which == 0) ? u_min
            : (which == 1) ? (u_min + kH)
            : (which == 2) ? v_min
                           : (v_min + kW);
    out_tail[i] = (float)val;
}

extern "C" void kernel_launch(void* const* d_in, const int* in_sizes, int n_in,
                              void* d_out, int out_size, void* d_ws, size_t ws_size,
                              hipStream_t stream) {
    const float* in  = (const float*)d_in[0];
    const int*   off = (const int*)d_in[1];
    float*       out = (float*)d_out;

    const unsigned blocks = (unsigned)(kNPlanes * kBlocksPerPlane);  // 4096
    axial_persist_kernel<<<dim3(blocks), dim3(kThreads), 0, stream>>>(in, off, out);
    axial_extras_kernel<<<dim3(1), dim3(64), 0, stream>>>(off, out + kOutElems);
}

// Round 10
// 474.507 us; speedup vs baseline: 1.1448x; 1.1448x over previous
//
#include <hip/hip_runtime.h>

// Input (16,32,382,255) f32 ; output tensor (16,32,765,765) f32
// + u_min/u_max/v_min/v_max (16 each) as floats after the tensor.
//
// out[b,c,u,v] = in[b,c,u-ulo,v-vlo] when (u-ulo) in [0,382) and (v-vlo) in
// [0,255), else 0.  ulo = 255-(q-r/2) in [1,382]; vlo = 382-r in [128,382].
//
// Wave specialization: fill blocks write ONLY the zero complement and contain
// NO loads (stores pipeline deep, rocclr-fill shape); copy blocks write ONLY
// the 255-dword copy spans (1:1 load:store, m13-copy shape). Disjoint regions
// -> no ordering requirement, minimal traffic (1.40 GB).
namespace {
constexpr int kC = 32;
constexpr int kH = 382;               // input rows
constexpr int kW = 255;               // input cols
constexpr int kS = 765;               // output edge
constexpr int kPlaneIn  = kH * kW;    // 97410
constexpr int kPlaneOut = kS * kS;    // 585225
constexpr int kNPlanes  = 512;        // 16*32
constexpr int kCopyChunks = 2;        // 191 input rows each
constexpr int kCopyRows   = 191;
constexpr int kFillChunks = 4;        // 192 output rows each
constexpr int kFillRows   = 192;
constexpr int kCopyBlocks = kNPlanes * kCopyChunks;   // 1024
constexpr int kFillBlocks = kNPlanes * kFillChunks;   // 2048
constexpr unsigned long long kOutElems =
    (unsigned long long)kNPlanes * (unsigned long long)kPlaneOut;
}

__global__ __launch_bounds__(256) void axial_split_kernel(
    const float* __restrict__ in, const int* __restrict__ off,
    float* __restrict__ out)
{
    const int bid = (int)blockIdx.x;

    if (bid < kCopyBlocks) {
        // ---------------- copy blocks: 4 waves, one input row per wave ----
        const int plane = bid >> 1;           // b*32 + c
        const int chunk = bid & 1;
        const int b     = plane >> 5;
        const int q   = off[2 * b];
        const int r   = off[2 * b + 1];
        const int ulo = 255 - (q - (r >> 1));
        const int vlo = 382 - r;

        const float* __restrict__ inplane = in + (size_t)plane * (size_t)kPlaneIn;
        const size_t pbase = (size_t)plane * (size_t)kPlaneOut;

        const int lane = (int)threadIdx.x & 63;
        const int sub  = (int)threadIdx.x >> 6;        // wave id 0..3
        const int h0 = chunk * kCopyRows;
        const int h1 = h0 + kCopyRows;                 // 191 or 382

        for (int hb = h0; hb < h1; hb += 4) {
            const int h = hb + sub;                    // this wave's input row
            if (h < h1) {
                const int u = ulo + h;
                const size_t span = pbase + (size_t)u * (size_t)kS + (size_t)vlo;
                const int pad  = (int)((0u - (unsigned)span) & 3u);
                const int nvec = (kW - pad) >> 2;      // 62 or 63
                const int tail = kW - pad - 4 * nvec;  // 0..3
                const float* __restrict__ inrow = inplane + (size_t)h * (size_t)kW;
                float* __restrict__ orow = out + span; // dword idx `span`

                if (lane < nvec) {
                    const int rel0 = pad + 4 * lane;   // in-col == span offset
                    float4 val = { inrow[rel0], inrow[rel0 + 1],
                                   inrow[rel0 + 2], inrow[rel0 + 3] };
                    *reinterpret_cast<float4*>(orow + rel0) = val;
                }
                if (lane < pad)  orow[lane] = inrow[lane];
                if (lane < tail) {
                    const int rel = pad + 4 * nvec + lane;
                    orow[rel] = inrow[rel];
                }
            }
        }
    } else {
        // ---------------- fill blocks: zero complement, NO loads ----------
        const int fid   = bid - kCopyBlocks;
        const int plane = fid >> 2;
        const int chunk = fid & 3;
        const int b     = plane >> 5;
        const int q   = off[2 * b];
        const int r   = off[2 * b + 1];
        const int ulo = 255 - (q - (r >> 1));
        const int uhi = ulo + kH;
        const int vlo = 382 - r;
        const int vhi = vlo + kW;

        const size_t pbase = (size_t)plane * (size_t)kPlaneOut;
        const int t  = (int)threadIdx.x;
        const int j0 = chunk * kFillRows;
        const int j1 = (j0 + kFillRows < kS) ? j0 + kFillRows : kS;

        for (int u = j0; u < j1; ++u) {
            const size_t rowbase = pbase + (size_t)u * (size_t)kS;
            const bool inband = (u >= ulo) && (u < uhi);

            // segment 1: dwords [0, s1n) of the row (s1n >= 128 always)
            {
                const int  s1n  = inband ? vlo : kS;
                const int  pad  = (int)((0u - (unsigned)rowbase) & 3u);
                const int  nvec = (s1n - pad) >> 2;
                const int  tail = s1n - pad - 4 * nvec;
                float* __restrict__ orow = out + rowbase;
                if (t < nvec) {
                    float4 z = {0.f, 0.f, 0.f, 0.f};
                    *reinterpret_cast<float4*>(orow + pad + 4 * t) = z;
                }
                if (t < pad)  orow[t] = 0.f;
                if (t < tail) orow[pad + 4 * nvec + t] = 0.f;
            }
            // segment 2 (in-band rows): dwords [vhi, 765)  (>=128 always)
            if (inband) {
                const size_t s2   = rowbase + (size_t)vhi;
                const int    n    = kS - vhi;
                const int    pad  = (int)((0u - (unsigned)s2) & 3u);
                const int    nvec = (n - pad) >> 2;
                const int    tail = n - pad - 4 * nvec;
                float* __restrict__ orow = out + s2;
                if (t < nvec) {
                    float4 z = {0.f, 0.f, 0.f, 0.f};
                    *reinterpret_cast<float4*>(orow + pad + 4 * t) = z;
                }
                if (t < pad)  orow[t] = 0.f;
                if (t < tail) orow[pad + 4 * nvec + t] = 0.f;
            }
        }
    }
}

// u_min = 255 - uoff ; u_max = u_min + 382 ; v_min = 382 - r ; v_max = v_min + 255
__global__ void axial_extras_kernel(const int* __restrict__ off,
                                    float* __restrict__ out_tail)
{
    int i = threadIdx.x;          // 0..63
    if (i >= 64) return;
    int b = i & 15;
    int which = i >> 4;           // 0:u_min 1:u_max 2:v_min 3:v_max
    int q = off[2 * b];
    int r = off[2 * b + 1];
    int uoff = q - (r >> 1);
    int u_min = 255 - uoff;
    int v_min = 382 - r;
    int val = (which == 0) ? u_min
            : (which == 1) ? (u_min + kH)
            : (which == 2) ? v_min
                           : (v_min + kW);
    out_tail[i] = (float)val;
}

extern "C" void kernel_launch(void* const* d_in, const int* in_sizes, int n_in,
                              void* d_out, int out_size, void* d_ws, size_t ws_size,
                              hipStream_t stream) {
    const float* in  = (const float*)d_in[0];
    const int*   off = (const int*)d_in[1];
    float*       out = (float*)d_out;

    const unsigned blocks = (unsigned)(kCopyBlocks + kFillBlocks);  // 3072
    axial_split_kernel<<<dim3(blocks), dim3(256), 0, stream>>>(in, off, out);
    axial_extras_kernel<<<dim3(1), dim3(64), 0, stream>>>(off, out + kOutElems);
}

// Round 11
// 323.578 us; speedup vs baseline: 1.6788x; 1.4664x over previous
//
#include <hip/hip_runtime.h>

// Input (16,32,382,255) f32 ; output tensor (16,32,765,765) f32
// + u_min/u_max/v_min/v_max (16 each) as floats after the tensor.
//
// out[b,c,u,v] = in[b,c,u-ulo,v-vlo] when (u-ulo) in [0,382), (v-vlo) in
// [0,255), else 0.  ulo = 255-(q-r/2) in [1,382]; vlo = 382-r in [128,382]
// -> the copy band is always fully interior (no clipping).
//
// Structure: hipMemsetAsync zeros the whole tensor using rocclr's
// fillBufferAligned (measured 6.5 TB/s on this buffer — none of our five
// hand-rolled store loops exceeded 3.6); then a lean band-copy kernel
// (1 wave per input row, aligned float4 stores) rewrites the 0.42 GB band.
namespace {
constexpr int kH = 382;               // input rows
constexpr int kW = 255;               // input cols
constexpr int kS = 765;               // output edge
constexpr int kPlaneIn  = kH * kW;    // 97410
constexpr int kPlaneOut = kS * kS;    // 585225
constexpr int kNPlanes  = 512;        // 16*32
constexpr int kTotalRows = kNPlanes * kH;        // 195584
constexpr int kBlocks    = 2048;
constexpr int kWavesTot  = kBlocks * 4;          // 8192 waves, ~24 rows each
constexpr unsigned long long kOutElems =
    (unsigned long long)kNPlanes * (unsigned long long)kPlaneOut;  // 299,635,200
}

__global__ __launch_bounds__(256) void band_copy_kernel(
    const float* __restrict__ in, const int* __restrict__ off,
    float* __restrict__ out)
{
    const int lane = (int)threadIdx.x & 63;
    const int gw   = (int)(blockIdx.x * 4u + ((unsigned)threadIdx.x >> 6));

    for (int R = gw; R < kTotalRows; R += kWavesTot) {
        const unsigned plane = (unsigned)R / 382u;          // const-div (mulhi)
        const int      h     = R - (int)(plane * 382u);     // input row
        const unsigned b     = plane >> 5;

        const int q   = off[2u * b];
        const int r   = off[2u * b + 1u];
        const int ulo = 255 - (q - (r >> 1));               // in [1,382]
        const int vlo = 382 - r;                            // in [128,382]

        const unsigned inbase = plane * (unsigned)kPlaneIn + (unsigned)h * (unsigned)kW;
        const unsigned S = plane * (unsigned)kPlaneOut
                         + (unsigned)(ulo + h) * (unsigned)kS + (unsigned)vlo;

        const int pad  = (int)((0u - S) & 3u);              // 16B-align the stores
        const int nvec = (kW - pad) >> 2;                   // 62 or 63
        const int tail = kW - pad - 4 * nvec;               // 0..3

        if (lane < nvec) {
            const int d = pad + 4 * lane;
            // scalar loads: input alignment differs from output; L1 absorbs
            float4 v = { in[inbase + d],     in[inbase + d + 1],
                         in[inbase + d + 2], in[inbase + d + 3] };
            *reinterpret_cast<float4*>(out + S + d) = v;
        }
        if (lane < pad)  out[S + lane] = in[inbase + lane];
        if (lane < tail) {
            const int d = pad + 4 * nvec + lane;
            out[S + d] = in[inbase + d];
        }
    }
}

// u_min = 255 - uoff ; u_max = u_min + 382 ; v_min = 382 - r ; v_max = v_min + 255
__global__ void axial_extras_kernel(const int* __restrict__ off,
                                    float* __restrict__ out_tail)
{
    int i = threadIdx.x;          // 0..63
    if (i >= 64) return;
    int b = i & 15;
    int which = i >> 4;           // 0:u_min 1:u_max 2:v_min 3:v_max
    int q = off[2 * b];
    int r = off[2 * b + 1];
    int uoff = q - (r >> 1);
    int u_min = 255 - uoff;
    int v_min = 382 - r;
    int val = (which == 0) ? u_min
            : (which == 1) ? (u_min + kH)
            : (which == 2) ? v_min
                           : (v_min + kW);
    out_tail[i] = (float)val;
}

extern "C" void kernel_launch(void* const* d_in, const int* in_sizes, int n_in,
                              void* d_out, int out_size, void* d_ws, size_t ws_size,
                              hipStream_t stream) {
    const float* in  = (const float*)d_in[0];
    const int*   off = (const int*)d_in[1];
    float*       out = (float*)d_out;

    // Bulk zero via rocclr fill kernel (6.5 TB/s measured on this buffer).
    hipMemsetAsync(out, 0, kOutElems * sizeof(float), stream);
    // Rewrite the interior copy band (0.62 GB traffic).
    band_copy_kernel<<<dim3(kBlocks), dim3(256), 0, stream>>>(in, off, out);
    // Tail: u_min/u_max/v_min/v_max as floats.
    axial_extras_kernel<<<dim3(1), dim3(64), 0, stream>>>(off, out + kOutElems);
}